// Round 6
// baseline (1409.289 us; speedup 1.0000x reference)
//
#include <hip/hip_runtime.h>
#include <hip/hip_bf16.h>

#define D 128
#define RT 64    // gemm rows per block
#define BK 64    // nodes per coarse bucket
#define CAP 2048 // edge capacity per bucket (mean 1024; P(overflow) ~ e^-250)
#define PAD 16   // cursor stride in ints = 64 B (one cache line per cursor)

typedef __attribute__((ext_vector_type(8))) short short8;
typedef __attribute__((ext_vector_type(4))) float floatx4;

__device__ __forceinline__ ushort f2bf(float v) {
  return __hip_bfloat16_raw(__float2bfloat16(v)).x;  // RNE
}
__device__ __forceinline__ float bf2f(ushort u) {
  return __uint_as_float((unsigned)u << 16);
}

// ---------------------------------------------------------------------------
// K1: blocks [0, GB): y = bf16(x @ W^T) via 16x16x32 bf16 MFMA (R5-proven).
// Blocks [GB, GB+CB): init padded bucket cursors to bk*CAP.
// ---------------------------------------------------------------------------
__global__ __launch_bounds__(256) void k1_gemm(
    const float* __restrict__ x, const float* __restrict__ W,
    ushort* __restrict__ y, int* __restrict__ cursor, int N, int GB, int NBK) {
  if (blockIdx.x >= GB) {
    int i = (blockIdx.x - GB) * 256 + threadIdx.x;
    if (i < NBK) cursor[i * PAD] = i * CAP;
    return;
  }
  __shared__ __align__(16) ushort sX[RT * 136];
  __shared__ __align__(16) ushort sW[128 * 136];

  int tid = threadIdx.x;
  int rowBase = blockIdx.x * RT;

#pragma unroll
  for (int it = 0; it < 16; it++) {
    int i = tid + it * 256;
    int r = i >> 5;
    int c4 = i & 31;
    float4 v = *(const float4*)(W + r * 128 + c4 * 4);
    *(ushort4*)&sW[r * 136 + c4 * 4] =
        make_ushort4(f2bf(v.x), f2bf(v.y), f2bf(v.z), f2bf(v.w));
  }
#pragma unroll
  for (int it = 0; it < 8; it++) {
    int i = tid + it * 256;
    int r = i >> 5;
    int c4 = i & 31;
    int row = rowBase + r;
    float4 v = (row < N) ? *(const float4*)(x + (long long)row * 128 + c4 * 4)
                         : make_float4(0.f, 0.f, 0.f, 0.f);
    *(ushort4*)&sX[r * 136 + c4 * 4] =
        make_ushort4(f2bf(v.x), f2bf(v.y), f2bf(v.z), f2bf(v.w));
  }
  __syncthreads();

  int wv = tid >> 6;
  int lane = tid & 63;
  int m = lane & 15;
  int q = lane >> 4;

  const ushort* aRow = &sX[(wv * 16 + m) * 136 + q * 8];
  const ushort* bRow = &sW[m * 136 + q * 8];

  floatx4 acc[8];
#pragma unroll
  for (int ct = 0; ct < 8; ct++) acc[ct] = (floatx4){0.f, 0.f, 0.f, 0.f};

#pragma unroll
  for (int ks = 0; ks < 4; ks++) {
    short8 a = *(const short8*)(aRow + ks * 32);
#pragma unroll
    for (int ct = 0; ct < 8; ct++) {
      short8 b = *(const short8*)(bRow + ct * 16 * 136 + ks * 32);
      acc[ct] = __builtin_amdgcn_mfma_f32_16x16x32_bf16(a, b, acc[ct], 0, 0, 0);
    }
  }

  int row0 = rowBase + wv * 16 + q * 4;
#pragma unroll
  for (int r = 0; r < 4; r++) {
    int row = row0 + r;
    if (row < N) {
      ushort* yp = y + (long long)row * 128 + m;
#pragma unroll
      for (int ct = 0; ct < 8; ct++) yp[ct * 16] = f2bf(acc[ct][r]);
    }
  }
}

// ---------------------------------------------------------------------------
// Fill: 1 edge/thread. Atomic on line-padded coarse cursor (1563 buckets);
// packed store (src | dlow<<26, w). Tail working set = 1563 lines (100 KB)
// -> L2/L3 merge lines, no per-store HBM eviction.
// ---------------------------------------------------------------------------
__global__ __launch_bounds__(256) void fill_bucket(const int* __restrict__ ei,
                                                   const float* __restrict__ ew,
                                                   int* __restrict__ cursor,
                                                   int2* __restrict__ bucket,
                                                   int E) {
  int e = blockIdx.x * 256 + threadIdx.x;
  if (e >= E) return;
  int s = ei[e];
  int d = ei[E + e];
  float w = ew[e];
  int bk = d >> 6;
  int p = atomicAdd(&cursor[bk * PAD], 1);  // absolute position (init bk*CAP)
  bucket[p] = make_int2(s | ((d & 63) << 26), __float_as_int(w));
}

// ---------------------------------------------------------------------------
// Pass 2: one block per bucket. 32 KB LDS fp32 accumulator for 64 nodes.
// Wave loads 64 edges' metadata coalesced, broadcasts via v_readlane (VALU),
// reads y[src] as two stride-1 ushort loads -> two conflict-free ds_add_f32.
// Epilogue: bias + coalesced fp32 store of final out rows.
// ---------------------------------------------------------------------------
__global__ __launch_bounds__(256) void bucket_acc(
    const ushort* __restrict__ y, const int2* __restrict__ bucket,
    const int* __restrict__ cursor, const float* __restrict__ bias,
    float* __restrict__ out, int N) {
  __shared__ float acc[BK * 128];  // 32 KB
  int tid = threadIdx.x;
  int bk = blockIdx.x;
  int base = bk * CAP;
  int cnt = cursor[bk * PAD] - base;

  for (int i = tid; i < BK * 128; i += 256) acc[i] = 0.f;
  __syncthreads();

  int wv = tid >> 6;
  int lane = tid & 63;

  for (int j0 = wv * 64; j0 < cnt; j0 += 256) {
    int idx = j0 + lane;
    int2 md = (idx < cnt) ? bucket[base + idx] : make_int2(0, 0);
    int mdx = md.x, mdy = md.y;
    int m = min(64, cnt - j0);
    int j = 0;
    for (; j + 4 <= m; j += 4) {
      int v0 = __builtin_amdgcn_readlane(mdx, j);
      int v1 = __builtin_amdgcn_readlane(mdx, j + 1);
      int v2 = __builtin_amdgcn_readlane(mdx, j + 2);
      int v3 = __builtin_amdgcn_readlane(mdx, j + 3);
      float w0 = __int_as_float(__builtin_amdgcn_readlane(mdy, j));
      float w1 = __int_as_float(__builtin_amdgcn_readlane(mdy, j + 1));
      float w2 = __int_as_float(__builtin_amdgcn_readlane(mdy, j + 2));
      float w3 = __int_as_float(__builtin_amdgcn_readlane(mdy, j + 3));
      int s0 = v0 & 0x03FFFFFF, d0 = (unsigned)v0 >> 26;
      int s1 = v1 & 0x03FFFFFF, d1 = (unsigned)v1 >> 26;
      int s2 = v2 & 0x03FFFFFF, d2 = (unsigned)v2 >> 26;
      int s3 = v3 & 0x03FFFFFF, d3 = (unsigned)v3 >> 26;
      ushort a0 = y[s0 * 128 + lane], b0 = y[s0 * 128 + 64 + lane];
      ushort a1 = y[s1 * 128 + lane], b1 = y[s1 * 128 + 64 + lane];
      ushort a2 = y[s2 * 128 + lane], b2 = y[s2 * 128 + 64 + lane];
      ushort a3 = y[s3 * 128 + lane], b3 = y[s3 * 128 + 64 + lane];
      atomicAdd(&acc[d0 * 128 + lane], w0 * bf2f(a0));
      atomicAdd(&acc[d0 * 128 + 64 + lane], w0 * bf2f(b0));
      atomicAdd(&acc[d1 * 128 + lane], w1 * bf2f(a1));
      atomicAdd(&acc[d1 * 128 + 64 + lane], w1 * bf2f(b1));
      atomicAdd(&acc[d2 * 128 + lane], w2 * bf2f(a2));
      atomicAdd(&acc[d2 * 128 + 64 + lane], w2 * bf2f(b2));
      atomicAdd(&acc[d3 * 128 + lane], w3 * bf2f(a3));
      atomicAdd(&acc[d3 * 128 + 64 + lane], w3 * bf2f(b3));
    }
    for (; j < m; j++) {
      int v0 = __builtin_amdgcn_readlane(mdx, j);
      float w0 = __int_as_float(__builtin_amdgcn_readlane(mdy, j));
      int s0 = v0 & 0x03FFFFFF, d0 = (unsigned)v0 >> 26;
      ushort a0 = y[s0 * 128 + lane], b0 = y[s0 * 128 + 64 + lane];
      atomicAdd(&acc[d0 * 128 + lane], w0 * bf2f(a0));
      atomicAdd(&acc[d0 * 128 + 64 + lane], w0 * bf2f(b0));
    }
  }
  __syncthreads();

  int node0 = bk * BK;
  for (int i = tid; i < BK * 32; i += 256) {
    int r = i >> 5;
    int c4 = i & 31;
    int node = node0 + r;
    if (node < N) {
      float4 v = *(float4*)&acc[r * 128 + c4 * 4];
      float4 bb = *(const float4*)(bias + c4 * 4);
      v.x += bb.x; v.y += bb.y; v.z += bb.z; v.w += bb.w;
      *(float4*)(out + (long long)node * 128 + c4 * 4) = v;
    }
  }
}

extern "C" void kernel_launch(void* const* d_in, const int* in_sizes, int n_in,
                              void* d_out, int out_size, void* d_ws,
                              size_t ws_size, hipStream_t stream) {
  const float* x = (const float*)d_in[0];
  const int* ei = (const int*)d_in[1];
  const float* ew = (const float*)d_in[2];
  const float* W = (const float*)d_in[3];
  const float* b = (const float*)d_in[4];

  int N = in_sizes[0] / D;  // 100000
  int E = in_sizes[2];      // 1600000
  int NBK = (N + BK - 1) / BK;  // 1563

  // Workspace: cursor (padded, 100 KB) | bucket int2[NBK*CAP] (25.6 MB) |
  //            y bf16[N*128] (25.6 MB)  -> ~51.3 MB total.
  int* cursor = (int*)d_ws;
  int2* bucket = (int2*)(cursor + (size_t)NBK * PAD);
  ushort* y = (ushort*)(bucket + (size_t)NBK * CAP);

  int GB = (N + RT - 1) / RT;       // 1563 gemm blocks
  int CB = (NBK + 255) / 256;       // 7 cursor-init blocks
  k1_gemm<<<GB + CB, 256, 0, stream>>>(x, W, y, cursor, N, GB, NBK);
  fill_bucket<<<(E + 255) / 256, 256, 0, stream>>>(ei, ew, cursor, bucket, E);
  bucket_acc<<<NBK, 256, 0, stream>>>(y, bucket, cursor, b, (float*)d_out, N);
}

// Round 7
// 299.589 us; speedup vs baseline: 4.7041x; 4.7041x over previous
//
#include <hip/hip_runtime.h>
#include <hip/hip_bf16.h>

#define D 128
#define RT 64    // gemm rows per block
#define BK 64    // nodes per coarse bucket
#define CAP 2048 // edge capacity per bucket (mean 1024; P(overflow) ~ e^-250)
#define PAD 16   // cursor stride in ints = 64 B (one line per cursor)

typedef __attribute__((ext_vector_type(8))) short short8;
typedef __attribute__((ext_vector_type(4))) float floatx4;

__device__ __forceinline__ ushort f2bf(float v) {
  return __hip_bfloat16_raw(__float2bfloat16(v)).x;  // RNE
}
__device__ __forceinline__ float bf2f(ushort u) {
  return __uint_as_float((unsigned)u << 16);
}

// ---------------------------------------------------------------------------
// K1 fused: blocks [0, GB): y = bf16(x @ W^T) via 16x16x32 bf16 MFMA
// (R5-proven).  Blocks [GB, GB+FB): coarse-bucket edge fill — latency-bound
// "air" (0.3% VALU in R2-R6) hidden under the GEMM's MFMA/VMEM work.
// ---------------------------------------------------------------------------
__global__ __launch_bounds__(256) void k1_gemm_fill(
    const float* __restrict__ x, const float* __restrict__ W,
    ushort* __restrict__ y, const int* __restrict__ ei,
    const float* __restrict__ ew, int* __restrict__ cursor,
    int2* __restrict__ bucket, int N, int E, int GB) {
  if (blockIdx.x >= GB) {
    // --- fill part: 1 edge/thread (TLP-fed; unrolling regressed in R3) ---
    int e = (blockIdx.x - GB) * 256 + threadIdx.x;
    if (e < E) {
      int s = ei[e];
      int d = ei[E + e];
      float w = ew[e];
      int bk = d >> 6;
      int p = atomicAdd(&cursor[bk * PAD], 1);  // relative (memset to 0)
      if (p < CAP)
        bucket[(long long)bk * CAP + p] =
            make_int2(s | ((d & 63) << 26), __float_as_int(w));
    }
    return;
  }
  // --- GEMM part (verbatim R5) ---
  __shared__ __align__(16) ushort sX[RT * 136];
  __shared__ __align__(16) ushort sW[128 * 136];

  int tid = threadIdx.x;
  int rowBase = blockIdx.x * RT;

#pragma unroll
  for (int it = 0; it < 16; it++) {
    int i = tid + it * 256;
    int r = i >> 5;
    int c4 = i & 31;
    float4 v = *(const float4*)(W + r * 128 + c4 * 4);
    *(ushort4*)&sW[r * 136 + c4 * 4] =
        make_ushort4(f2bf(v.x), f2bf(v.y), f2bf(v.z), f2bf(v.w));
  }
#pragma unroll
  for (int it = 0; it < 8; it++) {
    int i = tid + it * 256;
    int r = i >> 5;
    int c4 = i & 31;
    int row = rowBase + r;
    float4 v = (row < N) ? *(const float4*)(x + (long long)row * 128 + c4 * 4)
                         : make_float4(0.f, 0.f, 0.f, 0.f);
    *(ushort4*)&sX[r * 136 + c4 * 4] =
        make_ushort4(f2bf(v.x), f2bf(v.y), f2bf(v.z), f2bf(v.w));
  }
  __syncthreads();

  int wv = tid >> 6;
  int lane = tid & 63;
  int m = lane & 15;
  int q = lane >> 4;

  const ushort* aRow = &sX[(wv * 16 + m) * 136 + q * 8];
  const ushort* bRow = &sW[m * 136 + q * 8];

  floatx4 acc[8];
#pragma unroll
  for (int ct = 0; ct < 8; ct++) acc[ct] = (floatx4){0.f, 0.f, 0.f, 0.f};

#pragma unroll
  for (int ks = 0; ks < 4; ks++) {
    short8 a = *(const short8*)(aRow + ks * 32);
#pragma unroll
    for (int ct = 0; ct < 8; ct++) {
      short8 b = *(const short8*)(bRow + ct * 16 * 136 + ks * 32);
      acc[ct] = __builtin_amdgcn_mfma_f32_16x16x32_bf16(a, b, acc[ct], 0, 0, 0);
    }
  }

  int row0 = rowBase + wv * 16 + q * 4;
#pragma unroll
  for (int r = 0; r < 4; r++) {
    int row = row0 + r;
    if (row < N) {
      ushort* yp = y + (long long)row * 128 + m;
#pragma unroll
      for (int ct = 0; ct < 8; ct++) yp[ct * 16] = f2bf(acc[ct][r]);
    }
  }
}

// ---------------------------------------------------------------------------
// Sort-gather: one block per coarse bucket.
//  1) count per-node degrees in LDS (64 counters)
//  2) 64-wide exclusive scan
//  3) permute metadata into node-sorted order in 16 KB LDS
//  4) 4 waves x 16 nodes: R4-proven gather inner loop — wave-uniform
//     ds_read_b64 broadcast for metadata, ushort2/lane y-row load, 4-edge
//     unroll; fp32 accumulate; write out + bias (coalesced float2/lane).
// LDS ~17 KB -> ~6 resident blocks/CU (all 1563 blocks fit device-wide).
// ---------------------------------------------------------------------------
__global__ __launch_bounds__(256) void sort_gather(
    const ushort* __restrict__ y, const int2* __restrict__ bucket,
    const int* __restrict__ cursor, const float* __restrict__ bias,
    float* __restrict__ out, int N) {
  __shared__ __align__(16) int2 smd[CAP];  // node-sorted metadata, 16 KB
  __shared__ int sdeg[BK];
  __shared__ int soffs[BK];
  __shared__ int scur[BK];

  int tid = threadIdx.x;
  int bk = blockIdx.x;
  long long base = (long long)bk * CAP;
  int cnt = min(cursor[bk * PAD], CAP);

  if (tid < BK) sdeg[tid] = 0;
  __syncthreads();
  for (int i = tid; i < cnt; i += 256) {
    unsigned v = (unsigned)bucket[base + i].x;
    atomicAdd(&sdeg[v >> 26], 1);
  }
  __syncthreads();
  if (tid < BK) {
    int s = 0;
    for (int j = 0; j < tid; j++) s += sdeg[j];
    soffs[tid] = s;
    scur[tid] = s;
  }
  __syncthreads();
  for (int i = tid; i < cnt; i += 256) {
    int2 md = bucket[base + i];
    int d = (unsigned)md.x >> 26;
    int pos = atomicAdd(&scur[d], 1);
    smd[pos] = md;
  }
  __syncthreads();

  int wv = tid >> 6;
  int lane = tid & 63;
  const ushort2* yv = (const ushort2*)y;
  float2 bb = ((const float2*)bias)[lane];

  for (int nd = wv; nd < BK; nd += 4) {
    int node = bk * BK + nd;
    if (node >= N) continue;  // wave-uniform branch
    int st = soffs[nd];
    int c = sdeg[nd];
    float ax = 0.f, ay = 0.f;
    int j = 0;
    for (; j + 4 <= c; j += 4) {
      int2 m0 = smd[st + j];
      int2 m1 = smd[st + j + 1];
      int2 m2 = smd[st + j + 2];
      int2 m3 = smd[st + j + 3];
      int s0 = m0.x & 0x03FFFFFF, s1 = m1.x & 0x03FFFFFF;
      int s2 = m2.x & 0x03FFFFFF, s3 = m3.x & 0x03FFFFFF;
      float w0 = __int_as_float(m0.y), w1 = __int_as_float(m1.y);
      float w2 = __int_as_float(m2.y), w3 = __int_as_float(m3.y);
      ushort2 u0 = yv[(long long)s0 * 64 + lane];
      ushort2 u1 = yv[(long long)s1 * 64 + lane];
      ushort2 u2 = yv[(long long)s2 * 64 + lane];
      ushort2 u3 = yv[(long long)s3 * 64 + lane];
      ax += w0 * bf2f(u0.x) + w1 * bf2f(u1.x) + w2 * bf2f(u2.x) +
            w3 * bf2f(u3.x);
      ay += w0 * bf2f(u0.y) + w1 * bf2f(u1.y) + w2 * bf2f(u2.y) +
            w3 * bf2f(u3.y);
    }
    for (; j < c; j++) {
      int2 m0 = smd[st + j];
      int s0 = m0.x & 0x03FFFFFF;
      float w0 = __int_as_float(m0.y);
      ushort2 u0 = yv[(long long)s0 * 64 + lane];
      ax += w0 * bf2f(u0.x);
      ay += w0 * bf2f(u0.y);
    }
    float2 o = {ax + bb.x, ay + bb.y};
    ((float2*)out)[(long long)node * 64 + lane] = o;
  }
}

extern "C" void kernel_launch(void* const* d_in, const int* in_sizes, int n_in,
                              void* d_out, int out_size, void* d_ws,
                              size_t ws_size, hipStream_t stream) {
  const float* x = (const float*)d_in[0];
  const int* ei = (const int*)d_in[1];
  const float* ew = (const float*)d_in[2];
  const float* W = (const float*)d_in[3];
  const float* b = (const float*)d_in[4];

  int N = in_sizes[0] / D;      // 100000
  int E = in_sizes[2];          // 1600000
  int NBK = (N + BK - 1) / BK;  // 1563

  // Workspace: cursor (padded, 100 KB) | bucket int2[NBK*CAP] (25.6 MB) |
  //            y bf16[N*128] (25.6 MB)
  int* cursor = (int*)d_ws;
  int2* bucket = (int2*)(cursor + (size_t)NBK * PAD);
  ushort* y = (ushort*)(bucket + (size_t)NBK * CAP);

  hipMemsetAsync(cursor, 0, (size_t)NBK * PAD * sizeof(int), stream);

  int GB = (N + RT - 1) / RT;  // 1563 gemm blocks
  int FB = (E + 255) / 256;    // 6250 fill blocks
  k1_gemm_fill<<<GB + FB, 256, 0, stream>>>(x, W, y, ei, ew, cursor, bucket, N,
                                            E, GB);
  sort_gather<<<NBK, 256, 0, stream>>>(y, bucket, cursor, b, (float*)d_out, N);
}